// Round 2
// baseline (492.864 us; speedup 1.0000x reference)
//
#include <hip/hip_runtime.h>

// Problem dims (fixed)
#define B_DIM  2
#define C_DIM  8
#define F_DIM  1024
#define T_DIM  256
#define CH_DIM 32
#define FH_DIM 4096
#define BT_DIM 512   // B*T

typedef __bf16 bf16x8 __attribute__((ext_vector_type(8)));
typedef __bf16 bf16x4 __attribute__((ext_vector_type(4)));
typedef float  f32x4  __attribute__((ext_vector_type(4)));

__device__ __forceinline__ void async16(const void* g, void* l) {
  __builtin_amdgcn_global_load_lds(
      (const __attribute__((address_space(1))) unsigned int*)g,
      (__attribute__((address_space(3))) unsigned int*)l, 16, 0, 0);
}

// ---------------------------------------------------------------------------
// Kernel 1: LayerNorm over F (per b,c,t) + affine, written TRANSPOSED:
//   hn[c][b*T + t][f]  (bf16)
// ---------------------------------------------------------------------------
__global__ void ln_kernel(const float* __restrict__ x,
                          const float* __restrict__ lnw,
                          const float* __restrict__ lnb,
                          __bf16* __restrict__ hn) {
  const int tb = blockIdx.x;      // t-chunk of 16
  const int c  = blockIdx.y;
  const int b  = blockIdx.z;
  const int tid = threadIdx.x;
  const int tx = tid & 15, ty = tid >> 4;
  const int t0 = tb * 16;

  const float* xp = x + (size_t)(b * C_DIM + c) * F_DIM * T_DIM;

  float s = 0.f, s2 = 0.f;
  for (int f = ty; f < F_DIM; f += 16) {
    float v = xp[f * T_DIM + t0 + tx];
    s += v; s2 += v * v;
  }
  __shared__ float ps[16][16], ps2[16][16];
  __shared__ float mean_s[16], rstd_s[16];
  ps[ty][tx] = s; ps2[ty][tx] = s2;
  __syncthreads();
  if (tid < 16) {
    float a = 0.f, a2 = 0.f;
    for (int j = 0; j < 16; ++j) { a += ps[j][tid]; a2 += ps2[j][tid]; }
    float mu  = a * (1.0f / F_DIM);
    float var = a2 * (1.0f / F_DIM) - mu * mu;
    mean_s[tid] = mu;
    rstd_s[tid] = rsqrtf(var + 1e-8f);
  }
  __syncthreads();

  __shared__ float tile[64][17];
  __bf16* hp = hn + ((size_t)c * BT_DIM + b * T_DIM + t0) * F_DIM;
  for (int ff = 0; ff < 16; ++ff) {
    const int f0 = ff * 64;
#pragma unroll
    for (int it = 0; it < 4; ++it) {
      int e  = it * 256 + tid;
      int fi = e >> 4, ti = e & 15;
      float v = xp[(f0 + fi) * T_DIM + t0 + ti];
      v = (v - mean_s[ti]) * rstd_s[ti];
      v = v * lnw[c * F_DIM + f0 + fi] + lnb[c * F_DIM + f0 + fi];
      tile[fi][ti] = v;
    }
    __syncthreads();
#pragma unroll
    for (int it = 0; it < 4; ++it) {
      int e  = it * 256 + tid;
      int fx = e & 63, tw = e >> 6;
      hp[(size_t)tw * F_DIM + f0 + fx] = (__bf16)tile[fx][tw];
    }
    __syncthreads();
  }
}

// ---------------------------------------------------------------------------
// Kernel 2: deep-pipelined batched GEMM.  C[m][n] = sum_k A[m][k] * Bt[n][k]
//   A : fp32 [batch][M][K] weights (reg-staged fp32->bf16)
//   Bt: bf16 [batch][512][K] activations (k-minor), via global_load_lds
// Tile: BM=128, BN=512 (full N, so A is fetched from HBM exactly once),
// BK=32. Ring-3 LDS (120 KiB dynamic), counted vmcnt(6) (never 0 in loop),
// raw s_barrier, setprio around the 32-MFMA cluster.
// Grid: 256 blocks (1/CU), 512 threads (8 waves, 2M x 4N).
// Ledger (per iter T): issue A/B for slot (T+2)%3; vmcnt(6) => A(T+1) regs
// ready AND B(T+1) landed; ds_write A(T+1) -> slot (T+1)%3; barrier;
// ds_read+MFMA tile T from slot T%3; lgkmcnt(0); barrier.
// Slot being written always holds tile T-1/T-2 whose reads finished >=1
// barrier earlier. Clamped tail keeps vmcnt counts exact.
// ---------------------------------------------------------------------------
template<int MTBITS, bool CT>
__global__ __launch_bounds__(512, 2)
void gemm_pipe(const float* __restrict__ A,
               const __bf16* __restrict__ Bm,
               __bf16* __restrict__ Co,
               const int M, const int K) {
  const int MT  = 1 << MTBITS;
  const int bid = blockIdx.x;
  const int x   = bid & 7;          // XCD
  const int i   = bid >> 3;         // 0..31 within XCD
  const int batch = x * (32 >> MTBITS) + (i >> MTBITS);
  const int mt    = i & (MT - 1);

  const int tid  = threadIdx.x;
  const int lane = tid & 63;
  const int wid  = tid >> 6;

  const float*  Ab = A  + (size_t)batch * M * K + (size_t)(mt * 128) * K;
  const __bf16* Bb = Bm + (size_t)batch * BT_DIM * K;

  extern __shared__ __align__(16) char smem[];
  __bf16* Asb = (__bf16*)smem;                    // 3 x [128][32] = 24 KiB
  __bf16* Bsb = (__bf16*)(smem + 3 * 8192);       // 3 x [512][32] = 96 KiB

  // A staging: 2 float4 / tile / thread. j in {0,1}: row = j*64 + tid>>3,
  // cols = (tid&7)*4 .. +3  (global chunk per row = 128B contiguous)
  const int a_row0 = tid >> 3;
  const int a_col  = (tid & 7) * 4;
  // B staging: 4 global_load_lds(16B) / tile / thread; chunk = wid*4+j
  const int b_lrow = lane >> 2;
  const int b_lcol = (lane & 3) * 8;

  f32x4 acc[4][8] = {};
  const int wm  = (wid >> 2) * 64;     // 2 M-groups of 64
  const int wn  = (wid & 3) * 128;     // 4 N-groups of 128
  const int lr  = lane & 15;
  const int lk8 = (lane >> 4) * 8;

  const int KT = K >> 5;

  float4 sa0[2], sa1[2];

  auto issueA = [&](float4* S, int tt) {
#pragma unroll
    for (int j = 0; j < 2; ++j)
      S[j] = *(const float4*)(Ab + (size_t)(j * 64 + a_row0) * K + tt * 32 + a_col);
  };
  auto issueB = [&](int slot, int tt) {
    __bf16* dst = Bsb + slot * 16384;
#pragma unroll
    for (int j = 0; j < 4; ++j) {
      const int chunk = wid * 4 + j;
      async16(Bb + (size_t)(chunk * 16 + b_lrow) * K + tt * 32 + b_lcol,
              dst + chunk * 512);
    }
  };
  auto writeA = [&](const float4* S, int slot) {
    __bf16* dst = Asb + slot * 4096;
#pragma unroll
    for (int j = 0; j < 2; ++j) {
      bf16x4 v;
      v[0] = (__bf16)S[j].x; v[1] = (__bf16)S[j].y;
      v[2] = (__bf16)S[j].z; v[3] = (__bf16)S[j].w;
      *(bf16x4*)(dst + (j * 64 + a_row0) * 32 + a_col) = v;
    }
  };
  auto compute = [&](int slot) {
    const __bf16* As = Asb + slot * 4096;
    const __bf16* Bs = Bsb + slot * 16384;
    bf16x8 af[4], bfr[8];
#pragma unroll
    for (int mi = 0; mi < 4; ++mi)
      af[mi] = *(const bf16x8*)(As + (wm + mi * 16 + lr) * 32 + lk8);
#pragma unroll
    for (int ni = 0; ni < 8; ++ni)
      bfr[ni] = *(const bf16x8*)(Bs + (wn + ni * 16 + lr) * 32 + lk8);
    __builtin_amdgcn_s_setprio(1);
#pragma unroll
    for (int mi = 0; mi < 4; ++mi)
#pragma unroll
      for (int ni = 0; ni < 8; ++ni)
        acc[mi][ni] = __builtin_amdgcn_mfma_f32_16x16x32_bf16(af[mi], bfr[ni], acc[mi][ni], 0, 0, 0);
    __builtin_amdgcn_s_setprio(0);
  };

  // ---- prologue: tiles 0,1 in flight; A0 written; counts exact ----
  issueA(sa0, 0); issueB(0, 0);
  issueA(sa1, 1); issueB(1, 1);
  asm volatile("s_waitcnt vmcnt(10)" ::: "memory");   // A0 regs ready
  writeA(sa0, 0);
  asm volatile("s_waitcnt lgkmcnt(0)" ::: "memory");  // A0 visible pre-barrier

  // ---- main loop, unrolled x2 for static stage-reg sets ----
  for (int T = 0; T < KT; T += 2) {
    {
      const int tl = (T + 2 < KT) ? T + 2 : KT - 1;
      issueA(sa0, tl);
      issueB((T + 2) % 3, tl);
      asm volatile("s_waitcnt vmcnt(6)" ::: "memory"); // A(T+1) regs, B(T+1) landed
      writeA(sa1, (T + 1) % 3);
      __builtin_amdgcn_s_barrier();
      compute(T % 3);
      asm volatile("s_waitcnt lgkmcnt(0)" ::: "memory");
      __builtin_amdgcn_s_barrier();
    }
    {
      const int T1 = T + 1;
      const int tl = (T1 + 2 < KT) ? T1 + 2 : KT - 1;
      issueA(sa1, tl);
      issueB((T1 + 2) % 3, tl);
      asm volatile("s_waitcnt vmcnt(6)" ::: "memory");
      writeA(sa0, (T1 + 1) % 3);
      __builtin_amdgcn_s_barrier();
      compute(T1 % 3);
      asm volatile("s_waitcnt lgkmcnt(0)" ::: "memory");
      __builtin_amdgcn_s_barrier();
    }
  }

  // ---- epilogue: C/D frag map: col = lane&15, row = (lane>>4)*4 + reg ----
  const int col  = lane & 15;
  const int rowb = (lane >> 4) * 4;
#pragma unroll
  for (int mi = 0; mi < 4; ++mi) {
#pragma unroll
    for (int ni = 0; ni < 8; ++ni) {
      const int m = mt * 128 + wm + mi * 16 + rowb;
      const int n = wn + ni * 16 + col;
      if (CT) {
        bf16x4 o;
#pragma unroll
        for (int r = 0; r < 4; ++r) o[r] = (__bf16)acc[mi][ni][r];
        *(bf16x4*)(Co + ((size_t)batch * BT_DIM + n) * M + m) = o;
      } else {
#pragma unroll
        for (int r = 0; r < 4; ++r)
          Co[((size_t)batch * M + m + r) * BT_DIM + n] = (__bf16)acc[mi][ni][r];
      }
    }
  }
}

// ---------------------------------------------------------------------------
// Kernel 3: channel mix 8->32 + squared ReLU.
// ---------------------------------------------------------------------------
__global__ void mix1_kernel(const __bf16* __restrict__ Y1,
                            const float* __restrict__ dw1,
                            __bf16* __restrict__ h2) {
  const int gidx = blockIdx.x * 256 + threadIdx.x;
  const int g8 = gidx & 511, bt = gidx >> 9;
  const int g0 = g8 * 8;

  float y[C_DIM][8];
#pragma unroll
  for (int c = 0; c < C_DIM; ++c) {
    bf16x8 v = *(const bf16x8*)(Y1 + ((size_t)c * BT_DIM + bt) * FH_DIM + g0);
#pragma unroll
    for (int j = 0; j < 8; ++j) y[c][j] = (float)v[j];
  }
  for (int d = 0; d < CH_DIM; ++d) {
    float s[8] = {0.f,0.f,0.f,0.f,0.f,0.f,0.f,0.f};
#pragma unroll
    for (int c = 0; c < C_DIM; ++c) {
      const float wv = dw1[d * C_DIM + c];
#pragma unroll
      for (int j = 0; j < 8; ++j) s[j] += wv * y[c][j];
    }
    bf16x8 o;
#pragma unroll
    for (int j = 0; j < 8; ++j) {
      float r = s[j] > 0.f ? s[j] : 0.f;
      o[j] = (__bf16)(r * r);
    }
    *(bf16x8*)(h2 + ((size_t)d * BT_DIM + bt) * FH_DIM + g0) = o;
  }
}

// ---------------------------------------------------------------------------
// Kernel 4: channel mix 32->8 + residual.
// ---------------------------------------------------------------------------
__global__ void mix2_kernel(const float* __restrict__ x,
                            const __bf16* __restrict__ Y2,
                            const float* __restrict__ dw2,
                            float* __restrict__ out) {
  const int gidx = blockIdx.x * 256 + threadIdx.x;
  const int t4 = gidx & 63;
  const int f  = (gidx >> 6) & 1023;
  const int dd = (gidx >> 16) & 7;
  const int b  = gidx >> 19;
  const int t0 = t4 * 4;

  const size_t oidx = ((size_t)(b * C_DIM + dd) * F_DIM + f) * T_DIM + t0;
  float4 acc = *(const float4*)(x + oidx);
  for (int d = 0; d < CH_DIM; ++d) {
    const float wv = dw2[dd * CH_DIM + d];
    bf16x4 v = *(const bf16x4*)(Y2 + ((size_t)d * F_DIM + f) * BT_DIM + b * T_DIM + t0);
    acc.x += wv * (float)v[0];
    acc.y += wv * (float)v[1];
    acc.z += wv * (float)v[2];
    acc.w += wv * (float)v[3];
  }
  *(float4*)(out + oidx) = acc;
}

// ---------------------------------------------------------------------------
extern "C" void kernel_launch(void* const* d_in, const int* in_sizes, int n_in,
                              void* d_out, int out_size, void* d_ws, size_t ws_size,
                              hipStream_t stream) {
  const float* x   = (const float*)d_in[0];
  const float* lnw = (const float*)d_in[1];
  const float* lnb = (const float*)d_in[2];
  const float* pw1 = (const float*)d_in[3];
  const float* dw1 = (const float*)d_in[4];
  const float* pw2 = (const float*)d_in[5];
  const float* dw2 = (const float*)d_in[6];
  float* out = (float*)d_out;

  char* ws = (char*)d_ws;
  __bf16* hn = (__bf16*)(ws);                    // [C][512][F]    8 MB
  __bf16* Y1 = (__bf16*)(ws + (8ULL << 20));     // [C][512][Fh]  32 MB
  __bf16* h2 = (__bf16*)(ws + (40ULL << 20));    // [Ch][512][Fh] 128 MB
  __bf16* Y2 = (__bf16*)(ws);                    // [Ch][F][512]  32 MB (reuse)

  (void)hipFuncSetAttribute((const void*)gemm_pipe<5, true>,
                            hipFuncAttributeMaxDynamicSharedMemorySize, 122880);
  (void)hipFuncSetAttribute((const void*)gemm_pipe<3, false>,
                            hipFuncAttributeMaxDynamicSharedMemorySize, 122880);

  ln_kernel<<<dim3(T_DIM / 16, C_DIM, B_DIM), 256, 0, stream>>>(x, lnw, lnb, hn);
  // pw1: per c: [4096 x 1024] @ [1024 x 512] -> Y1^T [512][4096]
  gemm_pipe<5, true><<<256, 512, 122880, stream>>>(pw1, hn, Y1, FH_DIM, F_DIM);
  mix1_kernel<<<(BT_DIM * (FH_DIM / 8)) / 256, 256, 0, stream>>>(Y1, dw1, h2);
  // pw2: per d: [1024 x 4096] @ [4096 x 512] -> Y2 [1024][512]
  gemm_pipe<3, false><<<256, 512, 122880, stream>>>(pw2, h2, Y2, F_DIM, FH_DIM);
  mix2_kernel<<<(B_DIM * C_DIM * F_DIM * (T_DIM / 4)) / 256, 256, 0, stream>>>(x, Y2, dw2, out);
}

// Round 3
// 462.917 us; speedup vs baseline: 1.0647x; 1.0647x over previous
//
#include <hip/hip_runtime.h>

// Problem dims (fixed)
#define B_DIM  2
#define C_DIM  8
#define F_DIM  1024
#define T_DIM  256
#define CH_DIM 32
#define FH_DIM 4096
#define BT_DIM 512   // B*T

typedef __bf16 bf16x8 __attribute__((ext_vector_type(8)));
typedef __bf16 bf16x4 __attribute__((ext_vector_type(4)));
typedef float  f32x4  __attribute__((ext_vector_type(4)));

__device__ __forceinline__ void async16(const void* g, void* l) {
  __builtin_amdgcn_global_load_lds(
      (const __attribute__((address_space(1))) unsigned int*)g,
      (__attribute__((address_space(3))) unsigned int*)l, 16, 0, 0);
}

// ---------------------------------------------------------------------------
// Kernel 1: LayerNorm over F (per b,c,t) + affine, written TRANSPOSED:
//   hn[c][b*T + t][f]  (bf16)
// ---------------------------------------------------------------------------
__global__ void ln_kernel(const float* __restrict__ x,
                          const float* __restrict__ lnw,
                          const float* __restrict__ lnb,
                          __bf16* __restrict__ hn) {
  const int tb = blockIdx.x;      // t-chunk of 16
  const int c  = blockIdx.y;
  const int b  = blockIdx.z;
  const int tid = threadIdx.x;
  const int tx = tid & 15, ty = tid >> 4;
  const int t0 = tb * 16;

  const float* xp = x + (size_t)(b * C_DIM + c) * F_DIM * T_DIM;

  float s = 0.f, s2 = 0.f;
  for (int f = ty; f < F_DIM; f += 16) {
    float v = xp[f * T_DIM + t0 + tx];
    s += v; s2 += v * v;
  }
  __shared__ float ps[16][16], ps2[16][16];
  __shared__ float mean_s[16], rstd_s[16];
  ps[ty][tx] = s; ps2[ty][tx] = s2;
  __syncthreads();
  if (tid < 16) {
    float a = 0.f, a2 = 0.f;
    for (int j = 0; j < 16; ++j) { a += ps[j][tid]; a2 += ps2[j][tid]; }
    float mu  = a * (1.0f / F_DIM);
    float var = a2 * (1.0f / F_DIM) - mu * mu;
    mean_s[tid] = mu;
    rstd_s[tid] = rsqrtf(var + 1e-8f);
  }
  __syncthreads();

  __shared__ float tile[64][17];
  __bf16* hp = hn + ((size_t)c * BT_DIM + b * T_DIM + t0) * F_DIM;
  for (int ff = 0; ff < 16; ++ff) {
    const int f0 = ff * 64;
#pragma unroll
    for (int it = 0; it < 4; ++it) {
      int e  = it * 256 + tid;
      int fi = e >> 4, ti = e & 15;
      float v = xp[(f0 + fi) * T_DIM + t0 + ti];
      v = (v - mean_s[ti]) * rstd_s[ti];
      v = v * lnw[c * F_DIM + f0 + fi] + lnb[c * F_DIM + f0 + fi];
      tile[fi][ti] = v;
    }
    __syncthreads();
#pragma unroll
    for (int it = 0; it < 4; ++it) {
      int e  = it * 256 + tid;
      int fx = e & 63, tw = e >> 6;
      hp[(size_t)tw * F_DIM + f0 + fx] = (__bf16)tile[fx][tw];
    }
    __syncthreads();
  }
}

// ---------------------------------------------------------------------------
// Kernel 2: 256x256-tile batched GEMM, BK=64, double-buffered, 8 waves.
//   C[m][n] = sum_k A[m][k] * Bt[n][k]
//   A : fp32 [batch][M][K] weights, reg-staged fp32->bf16 -> ds_write
//   Bt: bf16 [batch][512][K] activations, global_load_lds (pre-swizzled src)
// LDS: 2 x (As[256][64] + Bs[256][64]) bf16 = 128 KiB, XOR swizzle
//   slot = c16 ^ (row & 7)  (involution, both sides).
// One __syncthreads per K-tile; per K-tile MFMA (~2400cy/block) >> HBM
// latency, prefetch issued 2 phases before the barrier drain.
// Grid 256 blocks (1/CU); same-batch tiles grouped per XCD for B L2 reuse.
// ---------------------------------------------------------------------------
template<int TPB_BITS, bool CT>   // tiles-per-batch = 1<<TPB_BITS
__global__ __launch_bounds__(512, 2)
void gemm256(const float* __restrict__ A, const __bf16* __restrict__ Bm,
             __bf16* __restrict__ Co, const int M, const int K) {
  const int bid = blockIdx.x;
  const int xcd = bid & 7, idx = bid >> 3;
  const int batch = xcd * (32 >> TPB_BITS) + (idx >> TPB_BITS);
  const int tile  = idx & ((1 << TPB_BITS) - 1);
  const int mt = tile >> 1, nt = tile & 1;

  const int tid  = threadIdx.x;
  const int lane = tid & 63;
  const int wid  = tid >> 6;

  const float*  Ab = A  + (size_t)batch * M * K + (size_t)(mt * 256) * K;
  const __bf16* Bb = Bm + (size_t)batch * BT_DIM * K + (size_t)(nt * 256) * K;

  extern __shared__ __align__(16) char smem[];
  __bf16* S = (__bf16*)smem;   // As[buf] @ buf*16384 ; Bs[buf] @ 32768+buf*16384

  f32x4 acc[8][4] = {};

  const int wm  = wid >> 2;          // m half (0..1) -> 128 rows
  const int wn  = wid & 3;           // n quarter (0..3) -> 64 rows
  const int lr  = lane & 15;
  const int khi = lane >> 4;         // 0..3

  const int a_row  = tid >> 1;       // 0..255
  const int a_half = tid & 1;        // which 32-float half of the 64-col row
  const int b_rlo  = lane >> 3;      // row within 8-row chunk
  const int b_swz  = (lane & 7) ^ b_rlo;  // pre-swizzled 16B slot in source

  const int NT = K >> 6;

  auto issueA = [&](float4* sa, int kt) {
    const float* p = Ab + (size_t)a_row * K + kt * 64 + a_half * 32;
#pragma unroll
    for (int i = 0; i < 8; ++i) sa[i] = *(const float4*)(p + i * 4);
  };
  auto issueB = [&](int buf, int kt) {
    __bf16* dstb = S + 32768 + buf * 16384;
#pragma unroll
    for (int j = 0; j < 4; ++j) {
      const int c = wid * 4 + j;   // 8-row chunk id (0..31)
      const __bf16* src = Bb + (size_t)(c * 8 + b_rlo) * K + kt * 64 + (b_swz << 3);
      async16(src, dstb + c * 512);
    }
  };
  auto writeA = [&](const float4* sa, int buf) {
    __bf16* dsta = S + buf * 16384 + a_row * 64;
    const int r7 = a_row & 7;
#pragma unroll
    for (int j = 0; j < 4; ++j) {
      const float4 u0 = sa[2 * j], u1 = sa[2 * j + 1];
      bf16x8 v;
      v[0] = (__bf16)u0.x; v[1] = (__bf16)u0.y; v[2] = (__bf16)u0.z; v[3] = (__bf16)u0.w;
      v[4] = (__bf16)u1.x; v[5] = (__bf16)u1.y; v[6] = (__bf16)u1.z; v[7] = (__bf16)u1.w;
      const int slot = (a_half * 4 + j) ^ r7;
      *(bf16x8*)(dsta + slot * 8) = v;
    }
  };
  auto phase = [&](int buf, int kk) {
    const __bf16* As = S + buf * 16384;
    const __bf16* Bs = S + 32768 + buf * 16384;
    const int cs = kk * 4 + khi;          // logical 16B col slot
    const int slot = cs ^ (lr & 7);       // swizzled (row&7 == lr&7 here)
    bf16x8 af[8], bq[4];
#pragma unroll
    for (int mi = 0; mi < 8; ++mi)
      af[mi] = *(const bf16x8*)(As + (wm * 128 + mi * 16 + lr) * 64 + slot * 8);
#pragma unroll
    for (int ni = 0; ni < 4; ++ni)
      bq[ni] = *(const bf16x8*)(Bs + (wn * 64 + ni * 16 + lr) * 64 + slot * 8);
    __builtin_amdgcn_s_setprio(1);
#pragma unroll
    for (int mi = 0; mi < 8; ++mi)
#pragma unroll
      for (int ni = 0; ni < 4; ++ni)
        acc[mi][ni] = __builtin_amdgcn_mfma_f32_16x16x32_bf16(af[mi], bq[ni], acc[mi][ni], 0, 0, 0);
    __builtin_amdgcn_s_setprio(0);
  };

  // ---- prologue: stage tile 0 into buf 0 ----
  {
    float4 sa[8];
    issueA(sa, 0);
    issueB(0, 0);
    writeA(sa, 0);        // compiler waits vmcnt for sa (B still in flight)
  }
  __syncthreads();        // drains vmcnt/lgkm -> tile 0 visible

  int cur = 0;
  for (int t = 0; t < NT; ++t) {
    const int tn = (t + 1 < NT) ? t + 1 : t;   // clamp: last iter re-stages (L2-hot)
    float4 sa[8];
    issueA(sa, tn);        // A first (older in vmcnt queue)
    issueB(cur ^ 1, tn);   // B after -> waiting for A leaves B in flight
    phase(cur, 0);
    writeA(sa, cur ^ 1);
    phase(cur, 1);
    __syncthreads();       // vmcnt(0) drain: B has had ~2 MFMA phases to land
    cur ^= 1;
  }

  // ---- epilogue: C/D map col = lane&15, row = (lane>>4)*4 + reg ----
  const int colc = lane & 15;
  const int rowb = (lane >> 4) * 4;
#pragma unroll
  for (int mi = 0; mi < 8; ++mi) {
#pragma unroll
    for (int ni = 0; ni < 4; ++ni) {
      const int m = mt * 256 + wm * 128 + mi * 16 + rowb;
      const int n = nt * 256 + wn * 64 + ni * 16 + colc;
      if (CT) {
        bf16x4 o;
#pragma unroll
        for (int r = 0; r < 4; ++r) o[r] = (__bf16)acc[mi][ni][r];
        *(bf16x4*)(Co + ((size_t)batch * BT_DIM + n) * M + m) = o;
      } else {
#pragma unroll
        for (int r = 0; r < 4; ++r)
          Co[((size_t)batch * M + m + r) * BT_DIM + n] = (__bf16)acc[mi][ni][r];
      }
    }
  }
}

// ---------------------------------------------------------------------------
// Kernel 3: channel mix 8->32 + squared ReLU.
// ---------------------------------------------------------------------------
__global__ void mix1_kernel(const __bf16* __restrict__ Y1,
                            const float* __restrict__ dw1,
                            __bf16* __restrict__ h2) {
  const int gidx = blockIdx.x * 256 + threadIdx.x;
  const int g8 = gidx & 511, bt = gidx >> 9;
  const int g0 = g8 * 8;

  float y[C_DIM][8];
#pragma unroll
  for (int c = 0; c < C_DIM; ++c) {
    bf16x8 v = *(const bf16x8*)(Y1 + ((size_t)c * BT_DIM + bt) * FH_DIM + g0);
#pragma unroll
    for (int j = 0; j < 8; ++j) y[c][j] = (float)v[j];
  }
  for (int d = 0; d < CH_DIM; ++d) {
    float s[8] = {0.f,0.f,0.f,0.f,0.f,0.f,0.f,0.f};
#pragma unroll
    for (int c = 0; c < C_DIM; ++c) {
      const float wv = dw1[d * C_DIM + c];
#pragma unroll
      for (int j = 0; j < 8; ++j) s[j] += wv * y[c][j];
    }
    bf16x8 o;
#pragma unroll
    for (int j = 0; j < 8; ++j) {
      float r = s[j] > 0.f ? s[j] : 0.f;
      o[j] = (__bf16)(r * r);
    }
    *(bf16x8*)(h2 + ((size_t)d * BT_DIM + bt) * FH_DIM + g0) = o;
  }
}

// ---------------------------------------------------------------------------
// Kernel 4: channel mix 32->8 + residual.
// ---------------------------------------------------------------------------
__global__ void mix2_kernel(const float* __restrict__ x,
                            const __bf16* __restrict__ Y2,
                            const float* __restrict__ dw2,
                            float* __restrict__ out) {
  const int gidx = blockIdx.x * 256 + threadIdx.x;
  const int t4 = gidx & 63;
  const int f  = (gidx >> 6) & 1023;
  const int dd = (gidx >> 16) & 7;
  const int b  = gidx >> 19;
  const int t0 = t4 * 4;

  const size_t oidx = ((size_t)(b * C_DIM + dd) * F_DIM + f) * T_DIM + t0;
  float4 acc = *(const float4*)(x + oidx);
  for (int d = 0; d < CH_DIM; ++d) {
    const float wv = dw2[dd * CH_DIM + d];
    bf16x4 v = *(const bf16x4*)(Y2 + ((size_t)d * F_DIM + f) * BT_DIM + b * T_DIM + t0);
    acc.x += wv * (float)v[0];
    acc.y += wv * (float)v[1];
    acc.z += wv * (float)v[2];
    acc.w += wv * (float)v[3];
  }
  *(float4*)(out + oidx) = acc;
}

// ---------------------------------------------------------------------------
extern "C" void kernel_launch(void* const* d_in, const int* in_sizes, int n_in,
                              void* d_out, int out_size, void* d_ws, size_t ws_size,
                              hipStream_t stream) {
  const float* x   = (const float*)d_in[0];
  const float* lnw = (const float*)d_in[1];
  const float* lnb = (const float*)d_in[2];
  const float* pw1 = (const float*)d_in[3];
  const float* dw1 = (const float*)d_in[4];
  const float* pw2 = (const float*)d_in[5];
  const float* dw2 = (const float*)d_in[6];
  float* out = (float*)d_out;

  char* ws = (char*)d_ws;
  __bf16* hn = (__bf16*)(ws);                    // [C][512][F]    8 MB
  __bf16* Y1 = (__bf16*)(ws + (8ULL << 20));     // [C][512][Fh]  32 MB
  __bf16* h2 = (__bf16*)(ws + (40ULL << 20));    // [Ch][512][Fh] 128 MB
  __bf16* Y2 = (__bf16*)(ws);                    // [Ch][F][512]  32 MB (reuse)

  (void)hipFuncSetAttribute((const void*)gemm256<5, true>,
                            hipFuncAttributeMaxDynamicSharedMemorySize, 131072);
  (void)hipFuncSetAttribute((const void*)gemm256<3, false>,
                            hipFuncAttributeMaxDynamicSharedMemorySize, 131072);

  ln_kernel<<<dim3(T_DIM / 16, C_DIM, B_DIM), 256, 0, stream>>>(x, lnw, lnb, hn);
  // pw1: per c: [4096 x 1024] @ [1024 x 512] -> Y1^T [512][4096]
  gemm256<5, true><<<256, 512, 131072, stream>>>(pw1, hn, Y1, FH_DIM, F_DIM);
  mix1_kernel<<<(BT_DIM * (FH_DIM / 8)) / 256, 256, 0, stream>>>(Y1, dw1, h2);
  // pw2: per d: [1024 x 4096] @ [4096 x 512] -> Y2 [1024][512]
  gemm256<3, false><<<256, 512, 131072, stream>>>(pw2, h2, Y2, F_DIM, FH_DIM);
  mix2_kernel<<<(B_DIM * C_DIM * F_DIM * (T_DIM / 4)) / 256, 256, 0, stream>>>(x, Y2, dw2, out);
}

// Round 4
// 404.663 us; speedup vs baseline: 1.2180x; 1.1440x over previous
//
#include <hip/hip_runtime.h>

// Problem dims (fixed)
#define B_DIM  2
#define C_DIM  8
#define F_DIM  1024
#define T_DIM  256
#define CH_DIM 32
#define FH_DIM 4096
#define BT_DIM 512   // B*T

typedef __bf16 bf16x8 __attribute__((ext_vector_type(8)));
typedef __bf16 bf16x4 __attribute__((ext_vector_type(4)));
typedef float  f32x4  __attribute__((ext_vector_type(4)));

__device__ __forceinline__ void async16(const void* g, void* l) {
  __builtin_amdgcn_global_load_lds(
      (const __attribute__((address_space(1))) unsigned int*)g,
      (__attribute__((address_space(3))) unsigned int*)l, 16, 0, 0);
}

// ---------------------------------------------------------------------------
// Kernel 1: LayerNorm over F (per b,c,t) + affine, written TRANSPOSED:
//   hn[c][b*T + t][f]  (bf16)
// ---------------------------------------------------------------------------
__global__ void ln_kernel(const float* __restrict__ x,
                          const float* __restrict__ lnw,
                          const float* __restrict__ lnb,
                          __bf16* __restrict__ hn) {
  const int tb = blockIdx.x;      // t-chunk of 16
  const int c  = blockIdx.y;
  const int b  = blockIdx.z;
  const int tid = threadIdx.x;
  const int tx = tid & 15, ty = tid >> 4;
  const int t0 = tb * 16;

  const float* xp = x + (size_t)(b * C_DIM + c) * F_DIM * T_DIM;

  float s = 0.f, s2 = 0.f;
  for (int f = ty; f < F_DIM; f += 16) {
    float v = xp[f * T_DIM + t0 + tx];
    s += v; s2 += v * v;
  }
  __shared__ float ps[16][16], ps2[16][16];
  __shared__ float mean_s[16], rstd_s[16];
  ps[ty][tx] = s; ps2[ty][tx] = s2;
  __syncthreads();
  if (tid < 16) {
    float a = 0.f, a2 = 0.f;
    for (int j = 0; j < 16; ++j) { a += ps[j][tid]; a2 += ps2[j][tid]; }
    float mu  = a * (1.0f / F_DIM);
    float var = a2 * (1.0f / F_DIM) - mu * mu;
    mean_s[tid] = mu;
    rstd_s[tid] = rsqrtf(var + 1e-8f);
  }
  __syncthreads();

  __shared__ float tile[64][17];
  __bf16* hp = hn + ((size_t)c * BT_DIM + b * T_DIM + t0) * F_DIM;
  for (int ff = 0; ff < 16; ++ff) {
    const int f0 = ff * 64;
#pragma unroll
    for (int it = 0; it < 4; ++it) {
      int e  = it * 256 + tid;
      int fi = e >> 4, ti = e & 15;
      float v = xp[(f0 + fi) * T_DIM + t0 + ti];
      v = (v - mean_s[ti]) * rstd_s[ti];
      v = v * lnw[c * F_DIM + f0 + fi] + lnb[c * F_DIM + f0 + fi];
      tile[fi][ti] = v;
    }
    __syncthreads();
#pragma unroll
    for (int it = 0; it < 4; ++it) {
      int e  = it * 256 + tid;
      int fx = e & 63, tw = e >> 6;
      hp[(size_t)tw * F_DIM + f0 + fx] = (__bf16)tile[fx][tw];
    }
    __syncthreads();
  }
}

// ---------------------------------------------------------------------------
// Kernel 2: 256x256 batched GEMM, BK=64, counted-vmcnt 4-phase pipeline.
//   C[m][n] = sum_k A[m][k] * Bt[n][k]
//   A : fp32 weights, reg-staged fp32->bf16, reg-prefetch distance 4 phases
//   Bt: bf16 activations (k-minor), global_load_lds into B ring-3
//       (prefetch distance 2 K-tiles = 8 phases)
// LDS 160KB: A dbuf 2x32KB + B ring 3x32KB. XOR swizzle slot^(row&7).
// NO vmcnt(0) in the loop: compiler's counted waits before writeA retire
// exactly what's needed; boundary = vmcnt(12) (steady-state no-op) +
// lgkmcnt(0) + bare s_barrier. 12 loads stay in flight across barriers.
// Grid 256 (1/CU), 512 thr (8 waves 2Mx4N, wave out = 128x64).
// ---------------------------------------------------------------------------
template<int TPB_BITS, bool CT>   // tiles-per-batch = 1<<TPB_BITS (mt x 2 nt)
__global__ __launch_bounds__(512, 2)
void gemm256(const float* __restrict__ A, const __bf16* __restrict__ Bm,
             __bf16* __restrict__ Co, const int M, const int K) {
  const int bid = blockIdx.x;
  const int xcd = bid & 7, idx = bid >> 3;
  const int batch = xcd * (32 >> TPB_BITS) + (idx >> TPB_BITS);
  const int tile  = idx & ((1 << TPB_BITS) - 1);
  const int mt = tile >> 1, nt = tile & 1;

  const int tid = threadIdx.x, lane = tid & 63, wid = tid >> 6;

  const float*  Ab = A  + (size_t)batch * M * K + (size_t)(mt * 256) * K;
  const __bf16* Bb = Bm + (size_t)batch * BT_DIM * K + (size_t)(nt * 256) * K;

  extern __shared__ __align__(16) char smem[];
  __bf16* const AS = (__bf16*)smem;            // 2 x 16384 elems (32KB each)
  __bf16* const BS = (__bf16*)(smem + 65536);  // 3 x 16384 elems

  const int a_row = tid >> 1, a_half = tid & 1, r7 = a_row & 7;
  const float* const aBase = Ab + (size_t)a_row * K + a_half * 32;
  const int b_c0  = wid * 4;
  const int b_rlo = lane >> 3;
  const int b_swz = (lane & 7) ^ b_rlo;   // pre-swizzled source slot

  const int wm = wid >> 2, wn = wid & 3;
  const int lr = lane & 15, khi = lane >> 4;
  const int lswz = lr & 7;

  f32x4 acc[8][4] = {};
  float4 sa[8];                      // A(t+?) staging regs (single set)

  const int NT = K >> 6;

  auto issueA_h = [&](int tt, int h) {
#pragma unroll
    for (int i = 0; i < 4; ++i)
      sa[h * 4 + i] = *(const float4*)(aBase + (size_t)tt * 64 + h * 16 + i * 4);
  };
  auto writeA_h = [&](int buf, int h) {
    __bf16* dst = AS + buf * 16384 + a_row * 64;
#pragma unroll
    for (int j = 2 * h; j < 2 * h + 2; ++j) {
      float4 u0 = sa[2 * j], u1 = sa[2 * j + 1];
      bf16x8 v;
      v[0]=(__bf16)u0.x; v[1]=(__bf16)u0.y; v[2]=(__bf16)u0.z; v[3]=(__bf16)u0.w;
      v[4]=(__bf16)u1.x; v[5]=(__bf16)u1.y; v[6]=(__bf16)u1.z; v[7]=(__bf16)u1.w;
      *(bf16x8*)(dst + (((a_half * 4 + j) ^ r7) << 3)) = v;
    }
  };
  auto issueB1 = [&](int rbuf, int tt, int j) {
    const int c = b_c0 + j;          // 8-row chunk 0..31
    async16(Bb + (size_t)(c * 8 + b_rlo) * K + (size_t)tt * 64 + (b_swz << 3),
            BS + rbuf * 16384 + c * 512);
  };
  auto readA4 = [&](bf16x8* af, int buf, int kk, int milo) {
    const __bf16* s = AS + buf * 16384;
    const int slot = ((kk * 4 + khi) ^ lswz) << 3;
#pragma unroll
    for (int mi = 0; mi < 4; ++mi)
      af[mi] = *(const bf16x8*)(s + (wm * 128 + (milo + mi) * 16 + lr) * 64 + slot);
  };
  auto readB4 = [&](bf16x8* bf, int rbuf, int kk) {
    const __bf16* s = BS + rbuf * 16384;
    const int slot = ((kk * 4 + khi) ^ lswz) << 3;
#pragma unroll
    for (int ni = 0; ni < 4; ++ni)
      bf[ni] = *(const bf16x8*)(s + (wn * 64 + ni * 16 + lr) * 64 + slot);
  };
  auto mfma16 = [&](const bf16x8* af, const bf16x8* bf, int milo) {
    __builtin_amdgcn_s_setprio(1);
#pragma unroll
    for (int mi = 0; mi < 4; ++mi)
#pragma unroll
      for (int ni = 0; ni < 4; ++ni)
        acc[milo + mi][ni] =
            __builtin_amdgcn_mfma_f32_16x16x32_bf16(af[mi], bf[ni], acc[milo + mi][ni], 0, 0, 0);
    __builtin_amdgcn_s_setprio(0);
  };

  // ---- prologue: A(0)->LDS, A(1)->regs, B(0)->ring0, B(1)->ring1 ----
  issueA_h(0, 0); issueA_h(0, 1);
  issueB1(0, 0, 0); issueB1(0, 0, 1); issueB1(0, 0, 2); issueB1(0, 0, 3);
  writeA_h(0, 0); writeA_h(0, 1);            // compiler: vmcnt(4) for sa
  issueA_h(1, 0); issueA_h(1, 1);
  issueB1(1, 1, 0); issueB1(1, 1, 1); issueB1(1, 1, 2); issueB1(1, 1, 3);
  asm volatile("s_waitcnt vmcnt(12)" ::: "memory");   // B(0) landed
  asm volatile("s_waitcnt lgkmcnt(0)" ::: "memory");  // A(0) writes visible
  __builtin_amdgcn_s_barrier();

  int cur = 0, rd = 0, st = 2;
  for (int t = 0; t < NT; ++t) {
    const int t2 = (t + 2 < NT) ? t + 2 : NT - 1;   // clamped: uniform ledger
    bf16x8 af[4], bf[4];
    // ---- p0: stage B(t+2)c0 | frags kk0 | MFMA mi0-3 x kk0 ----
    issueB1(st, t2, 0);
    readA4(af, cur, 0, 0);
    readB4(bf, rd, 0);
    __builtin_amdgcn_s_barrier();
    mfma16(af, bf, 0);
    __builtin_amdgcn_s_barrier();
    // ---- p1: stage B c1 | A frags mi4-7 | MFMA mi4-7 x kk0 ----
    issueB1(st, t2, 1);
    readA4(af, cur, 0, 4);
    __builtin_amdgcn_s_barrier();
    mfma16(af, bf, 4);
    __builtin_amdgcn_s_barrier();
    // ---- p2: stage B c2 | frags kk1 | writeA(t+1)h0 | issue A(t+2)h0 ----
    issueB1(st, t2, 2);
    readA4(af, cur, 1, 0);
    readB4(bf, rd, 1);
    writeA_h(cur ^ 1, 0);            // compiler: vmcnt(8) — counted, no drain
    issueA_h(t2, 0);
    __builtin_amdgcn_s_barrier();
    mfma16(af, bf, 0);
    __builtin_amdgcn_s_barrier();
    // ---- p3: stage B c3 | A frags mi4-7 kk1 | writeA h1 | issue A h1 ----
    issueB1(st, t2, 3);
    readA4(af, cur, 1, 4);
    writeA_h(cur ^ 1, 1);            // compiler: vmcnt(8)
    issueA_h(t2, 1);
    __builtin_amdgcn_s_barrier();
    mfma16(af, bf, 4);
    // ---- boundary: steady-state no-op wait; 12 loads stay in flight ----
    asm volatile("s_waitcnt vmcnt(12)" ::: "memory");
    asm volatile("s_waitcnt lgkmcnt(0)" ::: "memory");
    __builtin_amdgcn_s_barrier();
    cur ^= 1;
    rd = (rd == 2) ? 0 : rd + 1;
    st = (st == 2) ? 0 : st + 1;
  }

  // ---- epilogue: C/D map col = lane&15, row = (lane>>4)*4 + reg ----
  const int colc = lane & 15;
  const int rowb = (lane >> 4) * 4;
#pragma unroll
  for (int mi = 0; mi < 8; ++mi) {
#pragma unroll
    for (int ni = 0; ni < 4; ++ni) {
      const int m = mt * 256 + wm * 128 + mi * 16 + rowb;
      const int n = nt * 256 + wn * 64 + ni * 16 + colc;
      if (CT) {
        bf16x4 o;
#pragma unroll
        for (int r = 0; r < 4; ++r) o[r] = (__bf16)acc[mi][ni][r];
        *(bf16x4*)(Co + ((size_t)batch * BT_DIM + n) * M + m) = o;
      } else {
#pragma unroll
        for (int r = 0; r < 4; ++r)
          Co[((size_t)batch * M + m + r) * BT_DIM + n] = (__bf16)acc[mi][ni][r];
      }
    }
  }
}

// ---------------------------------------------------------------------------
// Kernel 3: channel mix 8->32 + squared ReLU.
// ---------------------------------------------------------------------------
__global__ void mix1_kernel(const __bf16* __restrict__ Y1,
                            const float* __restrict__ dw1,
                            __bf16* __restrict__ h2) {
  const int gidx = blockIdx.x * 256 + threadIdx.x;
  const int g8 = gidx & 511, bt = gidx >> 9;
  const int g0 = g8 * 8;

  float y[C_DIM][8];
#pragma unroll
  for (int c = 0; c < C_DIM; ++c) {
    bf16x8 v = *(const bf16x8*)(Y1 + ((size_t)c * BT_DIM + bt) * FH_DIM + g0);
#pragma unroll
    for (int j = 0; j < 8; ++j) y[c][j] = (float)v[j];
  }
  for (int d = 0; d < CH_DIM; ++d) {
    float s[8] = {0.f,0.f,0.f,0.f,0.f,0.f,0.f,0.f};
#pragma unroll
    for (int c = 0; c < C_DIM; ++c) {
      const float wv = dw1[d * C_DIM + c];
#pragma unroll
      for (int j = 0; j < 8; ++j) s[j] += wv * y[c][j];
    }
    bf16x8 o;
#pragma unroll
    for (int j = 0; j < 8; ++j) {
      float r = s[j] > 0.f ? s[j] : 0.f;
      o[j] = (__bf16)(r * r);
    }
    *(bf16x8*)(h2 + ((size_t)d * BT_DIM + bt) * FH_DIM + g0) = o;
  }
}

// ---------------------------------------------------------------------------
// Kernel 4: channel mix 32->8 + residual.
// ---------------------------------------------------------------------------
__global__ void mix2_kernel(const float* __restrict__ x,
                            const __bf16* __restrict__ Y2,
                            const float* __restrict__ dw2,
                            float* __restrict__ out) {
  const int gidx = blockIdx.x * 256 + threadIdx.x;
  const int t4 = gidx & 63;
  const int f  = (gidx >> 6) & 1023;
  const int dd = (gidx >> 16) & 7;
  const int b  = gidx >> 19;
  const int t0 = t4 * 4;

  const size_t oidx = ((size_t)(b * C_DIM + dd) * F_DIM + f) * T_DIM + t0;
  float4 acc = *(const float4*)(x + oidx);
  for (int d = 0; d < CH_DIM; ++d) {
    const float wv = dw2[dd * CH_DIM + d];
    bf16x4 v = *(const bf16x4*)(Y2 + ((size_t)d * F_DIM + f) * BT_DIM + b * T_DIM + t0);
    acc.x += wv * (float)v[0];
    acc.y += wv * (float)v[1];
    acc.z += wv * (float)v[2];
    acc.w += wv * (float)v[3];
  }
  *(float4*)(out + oidx) = acc;
}

// ---------------------------------------------------------------------------
extern "C" void kernel_launch(void* const* d_in, const int* in_sizes, int n_in,
                              void* d_out, int out_size, void* d_ws, size_t ws_size,
                              hipStream_t stream) {
  const float* x   = (const float*)d_in[0];
  const float* lnw = (const float*)d_in[1];
  const float* lnb = (const float*)d_in[2];
  const float* pw1 = (const float*)d_in[3];
  const float* dw1 = (const float*)d_in[4];
  const float* pw2 = (const float*)d_in[5];
  const float* dw2 = (const float*)d_in[6];
  float* out = (float*)d_out;

  char* ws = (char*)d_ws;
  __bf16* hn = (__bf16*)(ws);                    // [C][512][F]    8 MB
  __bf16* Y1 = (__bf16*)(ws + (8ULL << 20));     // [C][512][Fh]  32 MB
  __bf16* h2 = (__bf16*)(ws + (40ULL << 20));    // [Ch][512][Fh] 128 MB
  __bf16* Y2 = (__bf16*)(ws);                    // [Ch][F][512]  32 MB (reuse)

  (void)hipFuncSetAttribute((const void*)gemm256<5, true>,
                            hipFuncAttributeMaxDynamicSharedMemorySize, 163840);
  (void)hipFuncSetAttribute((const void*)gemm256<3, false>,
                            hipFuncAttributeMaxDynamicSharedMemorySize, 163840);

  ln_kernel<<<dim3(T_DIM / 16, C_DIM, B_DIM), 256, 0, stream>>>(x, lnw, lnb, hn);
  // pw1: per c: [4096 x 1024] @ [1024 x 512] -> Y1^T [512][4096]
  gemm256<5, true><<<256, 512, 163840, stream>>>(pw1, hn, Y1, FH_DIM, F_DIM);
  mix1_kernel<<<(BT_DIM * (FH_DIM / 8)) / 256, 256, 0, stream>>>(Y1, dw1, h2);
  // pw2: per d: [1024 x 4096] @ [4096 x 512] -> Y2 [1024][512]
  gemm256<3, false><<<256, 512, 163840, stream>>>(pw2, h2, Y2, F_DIM, FH_DIM);
  mix2_kernel<<<(B_DIM * C_DIM * F_DIM * (T_DIM / 4)) / 256, 256, 0, stream>>>(x, Y2, dw2, out);
}